// Round 8
// baseline (178.020 us; speedup 1.0000x reference)
//
#include <hip/hip_runtime.h>
#include <hip/hip_bf16.h>

typedef short bf16x8 __attribute__((ext_vector_type(8)));
typedef float f32x4  __attribute__((ext_vector_type(4)));

#define DEVINL static __device__ __forceinline__

DEVINL unsigned short f2bf(float x){
  union { float f; unsigned u; } v; v.f = x;
  unsigned r = v.u + 0x7fffu + ((v.u >> 16) & 1u);
  return (unsigned short)(r >> 16);
}
DEVINL float bf2f(unsigned short b){
  union { unsigned u; float f; } v; v.u = ((unsigned)b) << 16; return v.f;
}
DEVINL unsigned pk2(float a, float b){
  __hip_bfloat162 h = __float22bfloat162_rn(float2{a, b});
  union { __hip_bfloat162 h2; unsigned u; } cv; cv.h2 = h; return cv.u;
}
DEVINL float fexp2(float x){               // args bounded; skip OCML fixup
  float r; asm("v_exp_f32 %0, %1" : "=v"(r) : "v"(x)); return r;
}

// B=8, NH=8, H=W=32, L=1024, d=32. inputs row stride 768 (q|k|v each 256).
// 512-thread blocks (8 waves). Grid 512, XCD-swizzled: all 8 q-chunks of a
// (b,n) land on one XCD (x=bid&7 under round-robin dispatch) -> K/V slice
// (256KB) x 8 bns = 2MB resident in that XCD's 4MB L2; loads become L2 hits.
// Wave w: x1 = qc*4 + (w>>1), qh = w&1 (16 queries y1 = qh*16 + lane&15).
// QK^T swapped: S^T[key][q] = mfma(A=K, B=Q), C col=lane&15 (=q),
// row=4*(lane>>4)+r (=key). Fixed softmax ref m=8 (e^-8 cancels in O/l).
// P^T B-fragments in-register via v_permlane{32,16}_swap_b32 (r6-verified).
// 8 phases x 128 keys, LDS double-buffered. 2-DEEP register prefetch with
// write-late staging: loads for tile ph+2 issued at phase top; tile ph+1
// staged to LDS only AFTER phase ph's compute (counted vmcnt(4), ~1.5
// phases of latency cover). Raw s_barrier + lgkmcnt(0) only (no vmcnt
// drain at barrier).
__global__ __launch_bounds__(512, 4)
void aug_attn_kernel(const float* __restrict__ inp,
                     const float* __restrict__ relw,
                     const float* __restrict__ relh,
                     float* __restrict__ out)
{
  __shared__ __align__(16) unsigned short s_rw[128*66];    // RW[q][m]
  __shared__ __align__(16) unsigned short s_rh[128*34];    // RH[q][x2]
  __shared__ __align__(16) unsigned short s_k [2][128*40]; // K dbuf [key][d]
  __shared__ __align__(16) unsigned short s_vt[2][4096];   // V^T dbuf swizzled

  const int tid  = threadIdx.x;
  const int wv   = tid >> 6;
  const int lane = tid & 63;
  const int lo16 = lane & 15;
  const int hi4  = lane >> 4;

  // XCD swizzle: physical bid p -> (bn, qc) s.t. all qc of bn share p&7
  const int p   = blockIdx.x;
  const int xcd = p & 7;
  const int j   = p >> 3;
  const int bn  = xcd*8 + (j >> 3);
  const int qc  = j & 7;
  const int b   = bn >> 3;
  const int n   = bn & 7;
  const int x1l = wv >> 1;
  const int qh  = wv & 1;
  const int x1  = qc*4 + x1l;
  const int y1  = qh*16 + lo16;
  const int qrow = x1l*32 + y1;

  const float qscale = 0.17677669529663687f;
  const float L2E    = 1.44269504088896f;
  const float MFIX   = 8.0f;

  // ---- staging: thread -> key row tid>>2 (0..127), dims (tid&3)*8.. ------
  const int krow = tid >> 2;
  const int c8   = (tid & 3) * 8;
  const float* kbase = inp + ((size_t)(b*1024 + krow))*768 + 256 + n*32 + c8;
  const size_t kstep = (size_t)128*768;

  // V^T swizzled slots (loop-invariant): subtile vst, key vkr within it
  const int vst = krow >> 6, vkr = krow & 63;
  int vslot[8];
#pragma unroll
  for (int jj=0;jj<8;++jj){
    const int dv = c8 + jj;
    vslot[jj] = vst*2048 + dv*64 + (((vkr>>3) ^ (dv&7) ^ ((dv>>3)&3))<<3) + (vkr&7);
  }

  // 2-deep register tile buffers (static indexing only)
  float4 kR0a, kR0b, vR0a, vR0b;   // set 0
  float4 kR1a, kR1b, vR1a, vR1b;   // set 1

  // tile 0 -> set 0 (issued before prologue compute)
  kR0a = *(const float4*)(kbase);
  kR0b = *(const float4*)(kbase+4);
  vR0a = *(const float4*)(kbase+256);
  vR0b = *(const float4*)(kbase+260);

  // ---------------- Q fragment (B-operand: col=lo16, k=8*hi4+j) -----------
  bf16x8 qf;
  {
    const float* qp = inp + ((size_t)((b*32 + x1)*32 + y1))*768 + n*32 + hi4*8;
    float4 a = *(const float4*)qp;
    float4 c = *(const float4*)(qp+4);
    union { unsigned u[4]; bf16x8 v; } cv;
    cv.u[0]=pk2(a.x*qscale, a.y*qscale);
    cv.u[1]=pk2(a.z*qscale, a.w*qscale);
    cv.u[2]=pk2(c.x*qscale, c.y*qscale);
    cv.u[3]=pk2(c.z*qscale, c.w*qscale);
    qf = cv.v;
  }

  // ------------- RW table via MFMA: RW[q][m] = q . rel_w[m] ---------------
  // Wave writes rows [x1l*32+qh*16, +16) and reads only those -> no barrier.
#pragma unroll
  for (int mt=0; mt<4; ++mt){
    const int m = mt*16 + lo16;
    bf16x8 rf = {0,0,0,0,0,0,0,0};
    if (m < 63){
      const float* rp = relw + m*32 + hi4*8;
      float4 a = *(const float4*)rp;
      float4 c = *(const float4*)(rp+4);
      union { unsigned u[4]; bf16x8 v; } cv;
      cv.u[0]=pk2(a.x,a.y); cv.u[1]=pk2(a.z,a.w);
      cv.u[2]=pk2(c.x,c.y); cv.u[3]=pk2(c.z,c.w);
      rf = cv.v;
    }
    f32x4 acc = {0.f,0.f,0.f,0.f};
    acc = __builtin_amdgcn_mfma_f32_16x16x32_bf16(qf, rf, acc, 0,0,0);
    const int rw0 = x1l*32 + qh*16 + hi4*4;
#pragma unroll
    for (int r=0;r<4;++r)
      s_rw[(rw0+r)*66 + m] = f2bf(acc[r]);
  }

  // ------------- RH table (abs x2-form): RH[q][x2] = q . rel_h[x2-x1+31] --
#pragma unroll
  for (int mt=0; mt<4; ++mt){
    const int m = mt*16 + lo16;
    bf16x8 rf = {0,0,0,0,0,0,0,0};
    if (m < 63){
      const float* rp = relh + m*32 + hi4*8;
      float4 a = *(const float4*)rp;
      float4 c = *(const float4*)(rp+4);
      union { unsigned u[4]; bf16x8 v; } cv;
      cv.u[0]=pk2(a.x,a.y); cv.u[1]=pk2(a.z,a.w);
      cv.u[2]=pk2(c.x,c.y); cv.u[3]=pk2(c.z,c.w);
      rf = cv.v;
    }
    const int x2 = m + x1 - 31;
    f32x4 acc = {0.f,0.f,0.f,0.f};
    acc = __builtin_amdgcn_mfma_f32_16x16x32_bf16(qf, rf, acc, 0,0,0);
    if (x2 >= 0 && x2 < 32){
      const int rw0 = x1l*32 + qh*16 + hi4*4;
#pragma unroll
      for (int r=0;r<4;++r)
        s_rh[(rw0+r)*34 + x2] = f2bf(acc[r]);
    }
  }

  // ------------- hoist this lane's RW values (const over k-loop) ----------
  float rwl2[2][4];
  {
    const int mb = 31 - y1 + 4*hi4;        // in [0, 43]
#pragma unroll
    for (int pp=0;pp<2;++pp)
#pragma unroll
      for (int r=0;r<4;++r)
        rwl2[pp][r] = (bf2f(s_rw[qrow*66 + mb + 16*pp + r]) - MFIX)*L2E;
  }

  // ---- stage tile 0 -> buf[0]; issue tile 1 -> set 1 ----
  {
    uint4 kw; kw.x=pk2(kR0a.x,kR0a.y); kw.y=pk2(kR0a.z,kR0a.w);
              kw.z=pk2(kR0b.x,kR0b.y); kw.w=pk2(kR0b.z,kR0b.w);
    *(uint4*)(&s_k[0][krow*40 + c8]) = kw;
    const unsigned u0=pk2(vR0a.x,vR0a.y), u1=pk2(vR0a.z,vR0a.w);
    const unsigned u2=pk2(vR0b.x,vR0b.y), u3=pk2(vR0b.z,vR0b.w);
    unsigned short* vt = s_vt[0];
    vt[vslot[0]]=(unsigned short)u0;  vt[vslot[1]]=(unsigned short)(u0>>16);
    vt[vslot[2]]=(unsigned short)u1;  vt[vslot[3]]=(unsigned short)(u1>>16);
    vt[vslot[4]]=(unsigned short)u2;  vt[vslot[5]]=(unsigned short)(u2>>16);
    vt[vslot[6]]=(unsigned short)u3;  vt[vslot[7]]=(unsigned short)(u3>>16);
  }
  {
    const float* kp = kbase + kstep;
    kR1a = *(const float4*)(kp);
    kR1b = *(const float4*)(kp+4);
    vR1a = *(const float4*)(kp+256);
    vR1b = *(const float4*)(kp+260);
  }

  float l_run = 0.f;
  f32x4 accO[2];
  {
    f32x4 z = {0.f,0.f,0.f,0.f};
    accO[0] = z; accO[1] = z;
  }

#pragma unroll
  for (int ph=0; ph<8; ++ph){
    const int cur = ph & 1;
    // LDS-only barrier: buf[cur] writes (from prev iter / prologue) are
    // committed (lgkmcnt) then synced; vmcnt intentionally NOT drained.
    asm volatile("s_waitcnt lgkmcnt(0)" ::: "memory");
    __builtin_amdgcn_s_barrier();
    asm volatile("" ::: "memory");

    // issue tile ph+2 -> regset[cur] (its previous content was staged last iter)
    if (ph < 6){
      const float* kp = kbase + (size_t)(ph+2)*kstep;
      if (cur == 0){
        kR0a = *(const float4*)(kp);   kR0b = *(const float4*)(kp+4);
        vR0a = *(const float4*)(kp+256); vR0b = *(const float4*)(kp+260);
      } else {
        kR1a = *(const float4*)(kp);   kR1b = *(const float4*)(kp+4);
        vR1a = *(const float4*)(kp+256); vR1b = *(const float4*)(kp+260);
      }
    }

    // ---- compute on buf[cur]: two 64-key subtiles ----
#pragma unroll
    for (int st=0; st<2; ++st){
      bf16x8 kfrag[4];
#pragma unroll
      for (int kt=0;kt<4;++kt)
        kfrag[kt] = *(const bf16x8*)(&s_k[cur][(st*64 + kt*16 + lo16)*40 + hi4*8]);
      bf16x8 vfrag[2][2];
#pragma unroll
      for (int dvt=0;dvt<2;++dvt){
        const int dv = dvt*16 + lo16;
        const int xr = (dv&7) ^ ((dv>>3)&3);
#pragma unroll
        for (int kc=0;kc<2;++kc){
          const int blk = (kc*4 + hi4) ^ xr;
          vfrag[dvt][kc] = *(const bf16x8*)(&s_vt[cur][st*2048 + dv*64 + blk*8]);
        }
      }

      f32x4 S[4];
#pragma unroll
      for (int kt=0;kt<4;++kt){
        f32x4 z = {0.f,0.f,0.f,0.f};
        S[kt] = __builtin_amdgcn_mfma_f32_16x16x32_bf16(kfrag[kt], qf, z, 0,0,0);
      }

      const unsigned rhu = *(const unsigned*)(&s_rh[qrow*34 + 4*ph + 2*st]);
      const float rh0L = bf2f((unsigned short)(rhu & 0xffffu))*L2E;
      const float rh1L = bf2f((unsigned short)(rhu >> 16))*L2E;
      unsigned W[4][2];
      float lacc = 0.f;
#pragma unroll
      for (int kt=0;kt<4;++kt){
        const float rhL = (kt<2)? rh0L : rh1L;
        const int pp = kt & 1;
        float pv0 = fexp2(__builtin_fmaf(S[kt][0], L2E, rwl2[pp][0] + rhL));
        float pv1 = fexp2(__builtin_fmaf(S[kt][1], L2E, rwl2[pp][1] + rhL));
        float pv2 = fexp2(__builtin_fmaf(S[kt][2], L2E, rwl2[pp][2] + rhL));
        float pv3 = fexp2(__builtin_fmaf(S[kt][3], L2E, rwl2[pp][3] + rhL));
        lacc += (pv0+pv1) + (pv2+pv3);
        W[kt][0] = pk2(pv0, pv1);
        W[kt][1] = pk2(pv2, pv3);
      }
      l_run += lacc;

      bf16x8 pfrag[2];
#pragma unroll
      for (int kc=0;kc<2;++kc){
        unsigned r0 = W[2*kc][0],   r1 = W[2*kc][1];
        unsigned r2 = W[2*kc+1][0], r3 = W[2*kc+1][1];
        asm("v_permlane32_swap_b32 %0, %1" : "+v"(r0), "+v"(r2));
        asm("v_permlane32_swap_b32 %0, %1" : "+v"(r1), "+v"(r3));
        asm("v_permlane16_swap_b32 %0, %1" : "+v"(r0), "+v"(r2));
        asm("v_permlane16_swap_b32 %0, %1" : "+v"(r1), "+v"(r3));
        union { unsigned u[4]; bf16x8 v; } cv;
        cv.u[0]=r0; cv.u[1]=r1; cv.u[2]=r2; cv.u[3]=r3;
        pfrag[kc] = cv.v;
      }

#pragma unroll
      for (int kc=0;kc<2;++kc)
#pragma unroll
        for (int dvt=0;dvt<2;++dvt)
          accO[dvt] = __builtin_amdgcn_mfma_f32_16x16x32_bf16(
                        vfrag[dvt][kc], pfrag[kc], accO[dvt], 0,0,0);
    }

    // ---- write-late: stage tile ph+1 (regset[cur^1]) -> buf[cur^1] ------
    // Implicit wait here is a COUNTED vmcnt (tile ph+2's 4 loads outstanding).
    if (ph < 7){
      const int nxt = cur ^ 1;
      float4 ka, kb2, va, vb2;
      if (nxt == 0){ ka=kR0a; kb2=kR0b; va=vR0a; vb2=vR0b; }
      else         { ka=kR1a; kb2=kR1b; va=vR1a; vb2=vR1b; }
      uint4 kw; kw.x=pk2(ka.x,ka.y); kw.y=pk2(ka.z,ka.w);
                kw.z=pk2(kb2.x,kb2.y); kw.w=pk2(kb2.z,kb2.w);
      *(uint4*)(&s_k[nxt][krow*40 + c8]) = kw;
      const unsigned u0=pk2(va.x,va.y), u1=pk2(va.z,va.w);
      const unsigned u2=pk2(vb2.x,vb2.y), u3=pk2(vb2.z,vb2.w);
      unsigned short* vt = s_vt[nxt];
      vt[vslot[0]]=(unsigned short)u0;  vt[vslot[1]]=(unsigned short)(u0>>16);
      vt[vslot[2]]=(unsigned short)u1;  vt[vslot[3]]=(unsigned short)(u1>>16);
      vt[vslot[4]]=(unsigned short)u2;  vt[vslot[5]]=(unsigned short)(u2>>16);
      vt[vslot[6]]=(unsigned short)u3;  vt[vslot[7]]=(unsigned short)(u3>>16);
    }
  }

  // ---------------- epilogue: l reduce over hi4 group, out = O/l ----------
  float l = l_run;
  l += __shfl_xor(l, 16, 64);
  l += __shfl_xor(l, 32, 64);
  const float inv = 1.f / l;
  float* op = out + ((size_t)((b*32 + x1)*32 + y1))*256 + n*32;
#pragma unroll
  for (int dvt=0;dvt<2;++dvt){
    float4 o;
    o.x = accO[dvt][0]*inv;
    o.y = accO[dvt][1]*inv;
    o.z = accO[dvt][2]*inv;
    o.w = accO[dvt][3]*inv;
    *(float4*)(op + dvt*16 + hi4*4) = o;
  }
}

extern "C" void kernel_launch(void* const* d_in, const int* in_sizes, int n_in,
                              void* d_out, int out_size, void* d_ws, size_t ws_size,
                              hipStream_t stream) {
  (void)in_sizes; (void)n_in; (void)d_ws; (void)ws_size; (void)out_size;
  const float* inp  = (const float*)d_in[0];
  const float* relw = (const float*)d_in[1];
  const float* relh = (const float*)d_in[2];
  float* out = (float*)d_out;
  dim3 grid(512), block(512);
  aug_attn_kernel<<<grid, block, 0, stream>>>(inp, relw, relh, out);
}

// Round 9
// 102.105 us; speedup vs baseline: 1.7435x; 1.7435x over previous
//
#include <hip/hip_runtime.h>
#include <hip/hip_bf16.h>

typedef short bf16x8 __attribute__((ext_vector_type(8)));
typedef float f32x4  __attribute__((ext_vector_type(4)));

#define DEVINL static __device__ __forceinline__

DEVINL unsigned short f2bf(float x){
  union { float f; unsigned u; } v; v.f = x;
  unsigned r = v.u + 0x7fffu + ((v.u >> 16) & 1u);
  return (unsigned short)(r >> 16);
}
DEVINL float bf2f(unsigned short b){
  union { unsigned u; float f; } v; v.u = ((unsigned)b) << 16; return v.f;
}
DEVINL unsigned pk2(float a, float b){
  __hip_bfloat162 h = __float22bfloat162_rn(float2{a, b});
  union { __hip_bfloat162 h2; unsigned u; } cv; cv.h2 = h; return cv.u;
}
DEVINL float fexp2(float x){               // args bounded; skip OCML fixup
  float r; asm("v_exp_f32 %0, %1" : "=v"(r) : "v"(x)); return r;
}

// B=8, NH=8, H=W=32, L=1024, d=32. inputs row stride 768 (q|k|v each 256).
// 512-thread blocks (8 waves), grid 512.
// XCD SWIZZLE (the single delta vs r7): physical bid p -> xcd=p&7, j=p>>3,
// bn = xcd*8 + (j>>3), qc = j&7. Under round-robin dispatch (XCD = p%8),
// all 8 q-chunk blocks of one (b,n) land on ONE XCD; per-XCD co-resident
// working set = 8 bn x 256KB K/V = 2MB -> fits 4MB XCD L2, so the 8x
// K/V re-read is served by L2 instead of L3/HBM.
// Wave w: x1 = qc*4 + (w>>1), qh = w&1 (16 queries y1 = qh*16 + lane&15).
// QK^T swapped: S^T[key][q] = mfma(A=K, B=Q), C col=lane&15 (=q),
// row=4*(lane>>4)+r (=key). Fixed softmax ref m=8 (e^-8 cancels in O/l).
// P^T B-fragments in-register via v_permlane{32,16}_swap_b32 (r6-verified).
// 8 phases x 128 keys, LDS double-buffered, 1-deep register prefetch
// (r7-proven, VGPR 56, no spill). Raw s_barrier + lgkmcnt(0) only.
__global__ __launch_bounds__(512, 4)
void aug_attn_kernel(const float* __restrict__ inp,
                     const float* __restrict__ relw,
                     const float* __restrict__ relh,
                     float* __restrict__ out)
{
  __shared__ __align__(16) unsigned short s_rw[128*66];    // RW[q][m]
  __shared__ __align__(16) unsigned short s_rh[128*34];    // RH[q][x2]
  __shared__ __align__(16) unsigned short s_k [2][128*40]; // K dbuf [key][d]
  __shared__ __align__(16) unsigned short s_vt[2][4096];   // V^T dbuf swizzled

  const int tid  = threadIdx.x;
  const int wv   = tid >> 6;
  const int lane = tid & 63;
  const int lo16 = lane & 15;
  const int hi4  = lane >> 4;

  // XCD swizzle (bijective): group all q-chunks of a bn on one XCD
  const int p   = blockIdx.x;
  const int xcd = p & 7;
  const int j   = p >> 3;
  const int bn  = xcd*8 + (j >> 3);
  const int qc  = j & 7;
  const int b   = bn >> 3;
  const int n   = bn & 7;
  const int x1l = wv >> 1;
  const int qh  = wv & 1;
  const int x1  = qc*4 + x1l;
  const int y1  = qh*16 + lo16;
  const int qrow = x1l*32 + y1;

  const float qscale = 0.17677669529663687f;
  const float L2E    = 1.44269504088896f;
  const float MFIX   = 8.0f;

  // ---- staging: thread -> key row tid>>2 (0..127), dims (tid&3)*8.. ------
  const int krow = tid >> 2;
  const int c8   = (tid & 3) * 8;
  const float* kptr = inp + ((size_t)(b*1024 + krow))*768 + 256 + n*32 + c8;
  const float* vptr = kptr + 256;
  const size_t kstep = (size_t)128*768;

  float4 kA = *(const float4*)kptr;        // phase 0, issued early
  float4 kB = *(const float4*)(kptr+4);
  float4 vA = *(const float4*)vptr;
  float4 vB = *(const float4*)(vptr+4);

  // V^T swizzled slots (loop-invariant): subtile vst, key vkr within it
  const int vst = krow >> 6, vkr = krow & 63;
  int vslot[8];
#pragma unroll
  for (int jj=0;jj<8;++jj){
    const int dv = c8 + jj;
    vslot[jj] = vst*2048 + dv*64 + (((vkr>>3) ^ (dv&7) ^ ((dv>>3)&3))<<3) + (vkr&7);
  }

  // ---------------- Q fragment (B-operand: col=lo16, k=8*hi4+j) -----------
  bf16x8 qf;
  {
    const float* qp = inp + ((size_t)((b*32 + x1)*32 + y1))*768 + n*32 + hi4*8;
    float4 a = *(const float4*)qp;
    float4 c = *(const float4*)(qp+4);
    union { unsigned u[4]; bf16x8 v; } cv;
    cv.u[0]=pk2(a.x*qscale, a.y*qscale);
    cv.u[1]=pk2(a.z*qscale, a.w*qscale);
    cv.u[2]=pk2(c.x*qscale, c.y*qscale);
    cv.u[3]=pk2(c.z*qscale, c.w*qscale);
    qf = cv.v;
  }

  // ------------- RW table via MFMA: RW[q][m] = q . rel_w[m] ---------------
  // Wave writes rows [x1l*32+qh*16, +16) and reads only those -> no barrier.
#pragma unroll
  for (int mt=0; mt<4; ++mt){
    const int m = mt*16 + lo16;
    bf16x8 rf = {0,0,0,0,0,0,0,0};
    if (m < 63){
      const float* rp = relw + m*32 + hi4*8;
      float4 a = *(const float4*)rp;
      float4 c = *(const float4*)(rp+4);
      union { unsigned u[4]; bf16x8 v; } cv;
      cv.u[0]=pk2(a.x,a.y); cv.u[1]=pk2(a.z,a.w);
      cv.u[2]=pk2(c.x,c.y); cv.u[3]=pk2(c.z,c.w);
      rf = cv.v;
    }
    f32x4 acc = {0.f,0.f,0.f,0.f};
    acc = __builtin_amdgcn_mfma_f32_16x16x32_bf16(qf, rf, acc, 0,0,0);
    const int rw0 = x1l*32 + qh*16 + hi4*4;
#pragma unroll
    for (int r=0;r<4;++r)
      s_rw[(rw0+r)*66 + m] = f2bf(acc[r]);
  }

  // ------------- RH table (abs x2-form): RH[q][x2] = q . rel_h[x2-x1+31] --
#pragma unroll
  for (int mt=0; mt<4; ++mt){
    const int m = mt*16 + lo16;
    bf16x8 rf = {0,0,0,0,0,0,0,0};
    if (m < 63){
      const float* rp = relh + m*32 + hi4*8;
      float4 a = *(const float4*)rp;
      float4 c = *(const float4*)(rp+4);
      union { unsigned u[4]; bf16x8 v; } cv;
      cv.u[0]=pk2(a.x,a.y); cv.u[1]=pk2(a.z,a.w);
      cv.u[2]=pk2(c.x,c.y); cv.u[3]=pk2(c.z,c.w);
      rf = cv.v;
    }
    const int x2 = m + x1 - 31;
    f32x4 acc = {0.f,0.f,0.f,0.f};
    acc = __builtin_amdgcn_mfma_f32_16x16x32_bf16(qf, rf, acc, 0,0,0);
    if (x2 >= 0 && x2 < 32){
      const int rw0 = x1l*32 + qh*16 + hi4*4;
#pragma unroll
      for (int r=0;r<4;++r)
        s_rh[(rw0+r)*34 + x2] = f2bf(acc[r]);
    }
  }

  // ------------- hoist this lane's RW values (const over k-loop) ----------
  float rwl2[2][4];
  {
    const int mb = 31 - y1 + 4*hi4;        // in [0, 43]
#pragma unroll
    for (int pp=0;pp<2;++pp)
#pragma unroll
      for (int r=0;r<4;++r)
        rwl2[pp][r] = (bf2f(s_rw[qrow*66 + mb + 16*pp + r]) - MFIX)*L2E;
  }

  float l_run = 0.f;
  f32x4 accO[2];
  {
    f32x4 z = {0.f,0.f,0.f,0.f};
    accO[0] = z; accO[1] = z;
  }

  for (int ph=0; ph<8; ++ph){
    const int cur = ph & 1;
    // ---- stage phase ph (128 keys) -> buf[cur] from prefetched regs ----
    {
      uint4 kw; kw.x=pk2(kA.x,kA.y); kw.y=pk2(kA.z,kA.w);
                kw.z=pk2(kB.x,kB.y); kw.w=pk2(kB.z,kB.w);
      *(uint4*)(&s_k[cur][krow*40 + c8]) = kw;
      const unsigned u0=pk2(vA.x,vA.y), u1=pk2(vA.z,vA.w);
      const unsigned u2=pk2(vB.x,vB.y), u3=pk2(vB.z,vB.w);
      unsigned short* vt = s_vt[cur];
      vt[vslot[0]]=(unsigned short)u0;  vt[vslot[1]]=(unsigned short)(u0>>16);
      vt[vslot[2]]=(unsigned short)u1;  vt[vslot[3]]=(unsigned short)(u1>>16);
      vt[vslot[4]]=(unsigned short)u2;  vt[vslot[5]]=(unsigned short)(u2>>16);
      vt[vslot[6]]=(unsigned short)u3;  vt[vslot[7]]=(unsigned short)(u3>>16);
    }
    // LDS-only barrier: own writes committed (lgkmcnt), then sync. vmcnt
    // (the global prefetch) intentionally NOT drained here.
    asm volatile("s_waitcnt lgkmcnt(0)" ::: "memory");
    __builtin_amdgcn_s_barrier();
    asm volatile("" ::: "memory");

    // prefetch phase ph+1 globals (lands during this phase's compute)
    if (ph < 7){
      kptr += kstep; vptr += kstep;
      kA = *(const float4*)kptr; kB = *(const float4*)(kptr+4);
      vA = *(const float4*)vptr; vB = *(const float4*)(vptr+4);
    }

#pragma unroll
    for (int st=0; st<2; ++st){
      // ---- fragment loads for subtile st ----
      bf16x8 kfrag[4];
#pragma unroll
      for (int kt=0;kt<4;++kt)
        kfrag[kt] = *(const bf16x8*)(&s_k[cur][(st*64 + kt*16 + lo16)*40 + hi4*8]);
      bf16x8 vfrag[2][2];
#pragma unroll
      for (int dvt=0;dvt<2;++dvt){
        const int dv = dvt*16 + lo16;
        const int xr = (dv&7) ^ ((dv>>3)&3);
#pragma unroll
        for (int kc=0;kc<2;++kc){
          const int blk = (kc*4 + hi4) ^ xr;
          vfrag[dvt][kc] = *(const bf16x8*)(&s_vt[cur][st*2048 + dv*64 + blk*8]);
        }
      }

      // ---- S^T = K * Q^T ----
      f32x4 S[4];
#pragma unroll
      for (int kt=0;kt<4;++kt){
        f32x4 z = {0.f,0.f,0.f,0.f};
        S[kt] = __builtin_amdgcn_mfma_f32_16x16x32_bf16(kfrag[kt], qf, z, 0,0,0);
      }

      // ---- rel logits + exp (fixed m) -> packed P pairs ----
      const unsigned rhu = *(const unsigned*)(&s_rh[qrow*34 + 4*ph + 2*st]);
      const float rh0L = bf2f((unsigned short)(rhu & 0xffffu))*L2E;
      const float rh1L = bf2f((unsigned short)(rhu >> 16))*L2E;
      unsigned W[4][2];
      float lacc = 0.f;
#pragma unroll
      for (int kt=0;kt<4;++kt){
        const float rhL = (kt<2)? rh0L : rh1L;
        const int pp = kt & 1;
        float pv0 = fexp2(__builtin_fmaf(S[kt][0], L2E, rwl2[pp][0] + rhL));
        float pv1 = fexp2(__builtin_fmaf(S[kt][1], L2E, rwl2[pp][1] + rhL));
        float pv2 = fexp2(__builtin_fmaf(S[kt][2], L2E, rwl2[pp][2] + rhL));
        float pv3 = fexp2(__builtin_fmaf(S[kt][3], L2E, rwl2[pp][3] + rhL));
        lacc += (pv0+pv1) + (pv2+pv3);
        W[kt][0] = pk2(pv0, pv1);
        W[kt][1] = pk2(pv2, pv3);
      }
      l_run += lacc;

      // ---- P^T B-fragments in-register via permlane swaps (r6-verified) --
      bf16x8 pfrag[2];
#pragma unroll
      for (int kc=0;kc<2;++kc){
        unsigned r0 = W[2*kc][0],   r1 = W[2*kc][1];
        unsigned r2 = W[2*kc+1][0], r3 = W[2*kc+1][1];
        asm("v_permlane32_swap_b32 %0, %1" : "+v"(r0), "+v"(r2));
        asm("v_permlane32_swap_b32 %0, %1" : "+v"(r1), "+v"(r3));
        asm("v_permlane16_swap_b32 %0, %1" : "+v"(r0), "+v"(r2));
        asm("v_permlane16_swap_b32 %0, %1" : "+v"(r1), "+v"(r3));
        union { unsigned u[4]; bf16x8 v; } cv;
        cv.u[0]=r0; cv.u[1]=r1; cv.u[2]=r2; cv.u[3]=r3;
        pfrag[kc] = cv.v;
      }

      // ---- O^T += V^T * P^T ----
#pragma unroll
      for (int kc=0;kc<2;++kc)
#pragma unroll
        for (int dvt=0;dvt<2;++dvt)
          accO[dvt] = __builtin_amdgcn_mfma_f32_16x16x32_bf16(
                        vfrag[dvt][kc], pfrag[kc], accO[dvt], 0,0,0);
    }
  }

  // ---------------- epilogue: l reduce over hi4 group, out = O/l ----------
  float l = l_run;
  l += __shfl_xor(l, 16, 64);
  l += __shfl_xor(l, 32, 64);
  const float inv = 1.f / l;
  float* op = out + ((size_t)((b*32 + x1)*32 + y1))*256 + n*32;
#pragma unroll
  for (int dvt=0;dvt<2;++dvt){
    float4 o;
    o.x = accO[dvt][0]*inv;
    o.y = accO[dvt][1]*inv;
    o.z = accO[dvt][2]*inv;
    o.w = accO[dvt][3]*inv;
    *(float4*)(op + dvt*16 + hi4*4) = o;
  }
}

extern "C" void kernel_launch(void* const* d_in, const int* in_sizes, int n_in,
                              void* d_out, int out_size, void* d_ws, size_t ws_size,
                              hipStream_t stream) {
  (void)in_sizes; (void)n_in; (void)d_ws; (void)ws_size; (void)out_size;
  const float* inp  = (const float*)d_in[0];
  const float* relw = (const float*)d_in[1];
  const float* relh = (const float*)d_in[2];
  float* out = (float*)d_out;
  dim3 grid(512), block(512);
  aug_attn_kernel<<<grid, block, 0, stream>>>(inp, relw, relh, out);
}